// Round 1
// baseline (725.033 us; speedup 1.0000x reference)
//
#include <hip/hip_runtime.h>

#define TT 256
#define OBS 96
#define ACTD 32
#define HID 64
#define XHP 200   // padded bf16 row stride: 2-way LDS bank conflict (free) on ds_read_b128
#define EPS 1e-12f

typedef __bf16 bf16x8 __attribute__((ext_vector_type(8)));
typedef float f32x4 __attribute__((ext_vector_type(4)));
typedef unsigned short u16x8 __attribute__((ext_vector_type(8)));
typedef unsigned int u32;
typedef unsigned short u16;

__device__ __forceinline__ u16 f2bf(float f) {          // fp32 -> bf16 RNE
  u32 x = __builtin_bit_cast(u32, f);
  x += 0x7fffu + ((x >> 16) & 1u);
  return (u16)(x >> 16);
}
__device__ __forceinline__ u32 pk2bf(float a, float b) {
  return (u32)f2bf(a) | ((u32)f2bf(b) << 16);
}
__device__ __forceinline__ float sigm(float x) { return 1.0f / (1.0f + __expf(-x)); }
__device__ __forceinline__ float tanh_(float x) { return 1.0f - 2.0f / (__expf(2.0f * x) + 1.0f); }

// One block = 8 batch rows, all 256 time steps. 4 waves; wave w computes gate w
// (z columns [w*64, w*64+64)). MFMA 16x16x32_bf16, M rows 8..15 are hard zeros.
__global__ __launch_bounds__(256, 1) void lstm_fused(
    const float* __restrict__ obss, const float* __restrict__ actions,
    const float* __restrict__ Wm, const float* __restrict__ gamma,
    const float* __restrict__ beta, const float* __restrict__ dWv,
    const float* __restrict__ dbv, float* __restrict__ out)
{
  __shared__ u16 xh[16 * XHP];        // bf16 [16 rows][192+pad]: cols 0..127 = x_t, 128..191 = h_t
  __shared__ float gates[4][8][64];   // LN'd i,j,f,o
  __shared__ float cst[8][64];        // c state (post-LN, fp32)

  const int tid = threadIdx.x;
  const int wv = tid >> 6;            // wave id == gate id
  const int ln = tid & 63;
  const int l15 = ln & 15;            // MFMA: A row / B col / C col
  const int quad = ln >> 4;           // MFMA: k sub-offset / C row group
  const int n0 = blockIdx.x * 8;

  for (int i = tid; i < 16 * XHP / 2; i += 256) ((u32*)xh)[i] = 0u;  // h=0, pad rows=0
  for (int i = tid; i < 8 * 64; i += 256) ((float*)cst)[i] = 0.0f;   // c=0

  // --- W as per-lane B-fragments, resident in registers (96 VGPRs) ---
  // B-frag lane layout: elem j = W[k = kt*32 + quad*8 + j][col = wv*64 + nt*16 + l15]
  u16x8 bw[6][4];
  #pragma unroll
  for (int kt = 0; kt < 6; ++kt) {
    #pragma unroll
    for (int nt = 0; nt < 4; ++nt) {
      #pragma unroll
      for (int j = 0; j < 8; ++j) {
        float v = Wm[(kt * 32 + quad * 8 + j) * 256 + wv * 64 + nt * 16 + l15];
        bw[kt][nt][j] = f2bf(v);
      }
    }
  }

  float gg[4], gb[4];                 // this wave's gate gamma/beta per column tile
  #pragma unroll
  for (int nt = 0; nt < 4; ++nt) {
    gg[nt] = gamma[wv * 64 + nt * 16 + l15];
    gb[nt] = beta[wv * 64 + nt * 16 + l15];
  }

  const int em = tid >> 5;            // c-phase: row 0..7
  const int ec = (tid & 31) * 2;      // c-phase: 2 columns per thread
  const float cg0 = gamma[4 * 64 + ec], cg1 = gamma[4 * 64 + ec + 1];
  const float cb0 = beta[4 * 64 + ec],  cb1 = beta[4 * 64 + ec + 1];
  const float dw0 = dWv[ec], dw1 = dWv[ec + 1];
  const float bias = dbv[0];

  const int xr = tid >> 5;            // x loader: row 0..7
  const int xq = tid & 31;            // x loader: float4 index (24 obs + 8 act)
  const float* obs_p = obss + (size_t)(n0 + xr) * TT * OBS;
  const float* act_p = actions + (size_t)(n0 + xr) * TT * ACTD;

  __syncthreads();                    // zeros visible before x(0) store

  { // x(0) -> LDS (bf16)
    f32x4 x0;
    if (xq < 24) x0 = *(const f32x4*)(obs_p + xq * 4);
    else         x0 = *(const f32x4*)(act_p + (xq - 24) * 4);
    u32* dst = (u32*)(xh + xr * XHP + xq * 4);
    dst[0] = pk2bf(x0[0], x0[1]);
    dst[1] = pk2bf(x0[2], x0[3]);
  }
  __syncthreads();

  for (int t = 0; t < TT; ++t) {
    // ---- prefetch x(t+1) into registers (overlaps MFMA + LN) ----
    const int tn = (t < TT - 1) ? t + 1 : t;
    f32x4 xnx;
    if (xq < 24) xnx = *(const f32x4*)(obs_p + tn * OBS + xq * 4);
    else         xnx = *(const f32x4*)(act_p + tn * ACTD + (xq - 24) * 4);

    // ---- A-fragments: elem j = xh[row = l15][k = kt*32 + quad*8 + j] ----
    u16x8 af[6];
    #pragma unroll
    for (int kt = 0; kt < 6; ++kt)
      af[kt] = *(const u16x8*)(xh + l15 * XHP + kt * 32 + quad * 8);

    // ---- z tile: 4 N-tiles x 6 K-tiles of mfma_f32_16x16x32_bf16 ----
    f32x4 acc[4];
    #pragma unroll
    for (int nt = 0; nt < 4; ++nt) {
      f32x4 a = {0.0f, 0.0f, 0.0f, 0.0f};
      #pragma unroll
      for (int kt = 0; kt < 6; ++kt)
        a = __builtin_amdgcn_mfma_f32_16x16x32_bf16(
            __builtin_bit_cast(bf16x8, af[kt]),
            __builtin_bit_cast(bf16x8, bw[kt][nt]), a, 0, 0, 0);
      acc[nt] = a;
    }

    // ---- per-gate LayerNorm, fully in-wave ----
    // acc[nt][r] = z[row = quad*4 + r][col = nt*16 + l15] (gate wv)
    float s[4], ss[4];
    #pragma unroll
    for (int r = 0; r < 4; ++r) {
      s[r]  = acc[0][r] + acc[1][r] + acc[2][r] + acc[3][r];
      ss[r] = acc[0][r] * acc[0][r] + acc[1][r] * acc[1][r] +
              acc[2][r] * acc[2][r] + acc[3][r] * acc[3][r];
    }
    #pragma unroll
    for (int msk = 1; msk <= 8; msk <<= 1) {   // reduce 16 lanes within quad
      #pragma unroll
      for (int r = 0; r < 4; ++r) {
        s[r]  += __shfl_xor(s[r],  msk);
        ss[r] += __shfl_xor(ss[r], msk);
      }
    }
    if (ln < 32) {                              // quads 0,1 hold valid rows 0..7
      #pragma unroll
      for (int r = 0; r < 4; ++r) {
        const float mean = s[r] * (1.0f / 64.0f);
        const float var  = ss[r] * (1.0f / 64.0f) - mean * mean;
        const float rstd = rsqrtf(var + EPS);
        const int row = quad * 4 + r;
        #pragma unroll
        for (int nt = 0; nt < 4; ++nt)
          gates[wv][row][nt * 16 + l15] = (acc[nt][r] - mean) * rstd * gg[nt] + gb[nt];
      }
    }
    __syncthreads();

    // ---- c/h update: thread -> (row em, cols ec, ec+1) ----
    const float2 iv = *(const float2*)&gates[0][em][ec];
    const float2 jv = *(const float2*)&gates[1][em][ec];
    const float2 fv = *(const float2*)&gates[2][em][ec];
    const float2 ov = *(const float2*)&gates[3][em][ec];
    const float2 cv = *(const float2*)&cst[em][ec];
    float nc0 = cv.x * sigm(fv.x + 1.0f) + sigm(iv.x) * tanh_(jv.x);
    float nc1 = cv.y * sigm(fv.y + 1.0f) + sigm(iv.y) * tanh_(jv.y);
    float s2 = nc0 + nc1, ss2 = nc0 * nc0 + nc1 * nc1;
    #pragma unroll
    for (int msk = 1; msk <= 16; msk <<= 1) {  // reduce 32 lanes (one row = 64 cols)
      s2  += __shfl_xor(s2,  msk);
      ss2 += __shfl_xor(ss2, msk);
    }
    const float mean = s2 * (1.0f / 64.0f);
    const float var  = ss2 * (1.0f / 64.0f) - mean * mean;
    const float rstd = rsqrtf(var + EPS);
    const float c0 = (nc0 - mean) * rstd * cg0 + cb0;
    const float c1 = (nc1 - mean) * rstd * cg1 + cb1;
    *(float2*)&cst[em][ec] = make_float2(c0, c1);
    const float h0 = tanh_(c0) * sigm(ov.x);
    const float h1 = tanh_(c1) * sigm(ov.y);
    *(u32*)(xh + em * XHP + 128 + ec) = pk2bf(h0, h1);   // h(t+1) as bf16 A-input

    // ---- q[n,t] = h . dense_W + b ----
    float qp = h0 * dw0 + h1 * dw1;
    #pragma unroll
    for (int msk = 1; msk <= 16; msk <<= 1)
      qp += __shfl_xor(qp, msk);
    if ((tid & 31) == 0) out[(size_t)(n0 + em) * TT + t] = qp + bias;

    { // ---- commit prefetched x(t+1) ----
      u32* dst = (u32*)(xh + xr * XHP + xq * 4);
      dst[0] = pk2bf(xnx[0], xnx[1]);
      dst[1] = pk2bf(xnx[2], xnx[3]);
    }
    __syncthreads();
  }
}

extern "C" void kernel_launch(void* const* d_in, const int* in_sizes, int n_in,
                              void* d_out, int out_size, void* d_ws, size_t ws_size,
                              hipStream_t stream) {
  const float* obss    = (const float*)d_in[0];
  const float* actions = (const float*)d_in[1];
  const float* Wm      = (const float*)d_in[2];
  const float* gamma   = (const float*)d_in[3];
  const float* beta    = (const float*)d_in[4];
  const float* dWv     = (const float*)d_in[5];
  const float* dbv     = (const float*)d_in[6];
  float* out = (float*)d_out;
  lstm_fused<<<dim3(256), dim3(256), 0, stream>>>(obss, actions, Wm, gamma, beta,
                                                  dWv, dbv, out);
}